// Round 1
// baseline (3323.856 us; speedup 1.0000x reference)
//
#include <hip/hip_runtime.h>
#include <math.h>

#define LWI 96
#define LHI 96
#define HWD 384
#define NPIX 147456
#define LRPIX 9216
#define HID 256

__device__ __forceinline__ float gelu_f(float x){
  return 0.5f*x*(1.0f + erff(x*0.70710678118654752440f));
}

// jax.image.resize 'bilinear' (half-pixel, edge-renormalized == clamp) at scale 4
__device__ __forceinline__ float lr_up_at(const float* __restrict__ lr, int c, int y, int x){
  float sy = (y+0.5f)*0.25f - 0.5f;
  float sx = (x+0.5f)*0.25f - 0.5f;
  float fy = floorf(sy), fx = floorf(sx);
  float ty = sy - fy, tx = sx - fx;
  int y0 = (int)fy, x0 = (int)fx;
  int y0c = min(max(y0,0),LHI-1), y1c = min(max(y0+1,0),LHI-1);
  int x0c = min(max(x0,0),LWI-1), x1c = min(max(x0+1,0),LWI-1);
  const float* p = lr + c*LRPIX;
  float v00 = p[y0c*LWI+x0c], v01 = p[y0c*LWI+x1c];
  float v10 = p[y1c*LWI+x0c], v11 = p[y1c*LWI+x1c];
  return (1.f-ty)*((1.f-tx)*v00 + tx*v01) + ty*((1.f-tx)*v10 + tx*v11);
}

// one thread per (cout, y, x); 'SAME' zero padding; gelu at write
__global__ __launch_bounds__(256) void conv3x3_kernel(
    const float* __restrict__ in, const float* __restrict__ w,
    const float* __restrict__ b, float* __restrict__ out, int Cin){
  int tid = blockIdx.x*256 + threadIdx.x;           // o*9216 + y*96 + x
  int o = tid / LRPIX; int rem = tid - o*LRPIX;
  int y = rem / LWI;   int x = rem - y*LWI;
  int ou = __builtin_amdgcn_readfirstlane(o);
  float acc = b[ou];
  const float* wo = w + ou*Cin*9;
  for (int i=0;i<Cin;++i){
    const float* inp = in + i*LRPIX;
    #pragma unroll
    for (int dy=0;dy<3;++dy){
      int yy = y + dy - 1;
      bool yok = (yy>=0 && yy<LHI);
      #pragma unroll
      for (int dx=0;dx<3;++dx){
        int xx = x + dx - 1;
        float v = (yok && xx>=0 && xx<LWI) ? inp[yy*LWI+xx] : 0.0f;
        acc = fmaf(wo[i*9 + dy*3 + dx], v, acc);
      }
    }
  }
  out[tid] = gelu_f(acc);
}

__global__ __launch_bounds__(256) void conv1x1_kernel(
    const float* __restrict__ in, const float* __restrict__ w,
    const float* __restrict__ b, float* __restrict__ out,
    int wstride, int dogelu){
  int tid = blockIdx.x*256 + threadIdx.x;
  int o = tid / LRPIX; int p = tid - o*LRPIX;
  int ou = __builtin_amdgcn_readfirstlane(o);
  float acc = b[ou];
  const float* wo = w + ou*wstride;
  for (int i=0;i<64;++i) acc = fmaf(wo[i], in[i*LRPIX+p], acc);
  out[tid] = dogelu ? gelu_f(acc) : acc;
}

// 64 px per block, 512 threads (8 waves); wave w owns 32 output cols.
__device__ __forceinline__ void mlp_layer(const float* __restrict__ bin, float* __restrict__ bout,
                                          const float* __restrict__ W, const float* __restrict__ B,
                                          int K, int lane, int wu){
  float acc[32];
  #pragma unroll
  for (int j=0;j<32;++j) acc[j]=0.f;
  const float* Wp = W + wu*32;
  const float* hrow = bin + lane*257;
  for (int k=0;k<K;++k){
    float hv = hrow[k];
    const float* wr = Wp + k*HID;   // wave-uniform address -> scalar loads
    #pragma unroll
    for (int j=0;j<32;++j) acc[j] = fmaf(hv, wr[j], acc[j]);
  }
  #pragma unroll
  for (int j=0;j<32;++j){
    float v = acc[j] + B[wu*32+j];
    bout[lane*257 + wu*32 + j] = gelu_f(v);
  }
  __syncthreads();
}

__global__ __launch_bounds__(512) void mlp_kernel(
  const float* __restrict__ feat, const float* __restrict__ lr,
  const float* __restrict__ W0, const float* __restrict__ B0,
  const float* __restrict__ W1, const float* __restrict__ B1,
  const float* __restrict__ W2, const float* __restrict__ B2,
  const float* __restrict__ W3, const float* __restrict__ B3,
  const float* __restrict__ W4, const float* __restrict__ B4,
  const float* __restrict__ HKW, const float* __restrict__ HKB,
  const float* __restrict__ HGW, const float* __restrict__ HGB,
  float* __restrict__ sr)
{
  __shared__ float Abuf[64*257];
  __shared__ float Bbuf[64*257];
  int t = threadIdx.x;
  int lane = t & 63;
  int wu = __builtin_amdgcn_readfirstlane(t >> 6);   // 0..7
  int pix = blockIdx.x*64 + lane;
  int y = pix / HWD, x = pix - (pix / HWD)*HWD;
  float lx = (x+0.5f)*0.25f - 0.5f;
  float ly = (y+0.5f)*0.25f - 0.5f;
  float cxf = fminf(fmaxf(rintf(lx),0.f),95.f);      // round half-even, matches jnp.round
  float cyf = fminf(fmaxf(rintf(ly),0.f),95.f);
  int cxi = (int)cxf, cyi = (int)cyf;
  float dx = lx - cxf, dy = ly - cyf;

  // ---- build z[106] into Abuf ----
  {
    int base = cyi*LWI + cxi;
    float* zr = Abuf + lane*257;
    #pragma unroll
    for (int j=0;j<8;++j){
      int c = wu*8 + j;
      zr[c] = feat[c*LRPIX + base];
    }
    float xn = (x+0.5f)*(2.0f/384.0f) - 1.0f;
    float yn = (y+0.5f)*(2.0f/384.0f) - 1.0f;
    for (int bnd = wu; bnd < 10; bnd += 8){
      float fr = 3.14159265358979323846f * (float)(1<<bnd);
      float ax = xn*fr, ay = yn*fr;
      zr[64+4*bnd+0] = sinf(ax);
      zr[64+4*bnd+1] = cosf(ax);
      zr[64+4*bnd+2] = sinf(ay);
      zr[64+4*bnd+3] = cosf(ay);
    }
    if (wu==0){ zr[104]=dx; zr[105]=dy; }
  }
  __syncthreads();

  mlp_layer(Abuf, Bbuf, W0, B0, 106, lane, wu);
  mlp_layer(Bbuf, Abuf, W1, B1, 256, lane, wu);
  mlp_layer(Abuf, Bbuf, W2, B2, 256, lane, wu);
  mlp_layer(Bbuf, Abuf, W3, B3, 256, lane, wu);
  mlp_layer(Abuf, Bbuf, W4, B4, 256, lane, wu);
  // final h in Bbuf

  // ---- heads: klog[196] + glog[4] -> Abuf cols 0..199 (no gelu) ----
  {
    float acc[25];
    #pragma unroll
    for (int j=0;j<25;++j) acc[j]=0.f;
    const float* hrow = Bbuf + lane*257;
    for (int k=0;k<256;++k){
      float hv = hrow[k];
      #pragma unroll
      for (int j=0;j<25;++j){
        int col = wu*25 + j;
        float wv = (col < 196) ? HKW[k*196 + col] : HGW[k*4 + (col-196)];
        acc[j] = fmaf(hv, wv, acc[j]);
      }
    }
    #pragma unroll
    for (int j=0;j<25;++j){
      int col = wu*25+j;
      float bias = (col<196) ? HKB[col] : HGB[col-196];
      Abuf[lane*257+col] = acc[j] + bias;
    }
  }
  __syncthreads();

  // ---- softmax per head + gate softmax; gate-weighted kernels -> Bbuf ----
  if (t < 256){
    int p = t & 63; int hd = t >> 6;
    float* row = Abuf + p*257;
    float g0=row[196], g1=row[197], g2=row[198], g3=row[199];
    float gm = fmaxf(fmaxf(g0,g1),fmaxf(g2,g3));
    float e0=expf(g0-gm), e1=expf(g1-gm), e2=expf(g2-gm), e3=expf(g3-gm);
    float gs = e0+e1+e2+e3;
    float gate = ((hd==0)?e0:(hd==1)?e1:(hd==2)?e2:e3)/gs;
    float m = -1e30f;
    for (int k=0;k<49;++k) m = fmaxf(m, row[hd*49+k]);
    float s = 0.f;
    float* kout = Bbuf + p*257 + hd*49;
    for (int k=0;k<49;++k){ float e = expf(row[hd*49+k]-m); s += e; kout[k] = e; }
    float sc = gate/s;
    for (int k=0;k<49;++k) kout[k] *= sc;
  }
  __syncthreads();

  // ---- apply mixed kernel to 7x7 LR neighborhood ----
  if (t < 192){
    int p = t & 63; int c = t >> 6;       // lane==p, so cxi/cyi/pix are this pixel's
    const float* kb = Bbuf + p*257;
    const float* lrc = lr + c*LRPIX;
    float acc = 0.f;
    #pragma unroll
    for (int k=0;k<49;++k){
      float km = kb[k] + kb[49+k] + kb[98+k] + kb[147+k];
      int oy = k/7 - 3, ox = k - (k/7)*7 - 3;
      int ny = min(max(cyi+oy,0),95), nx = min(max(cxi+ox,0),95);
      acc = fmaf(km, lrc[ny*LWI+nx], acc);
    }
    sr[c*NPIX + pix] = acc;
  }
}

// fused grouped-conv refiner + gray-residual fusion; 16x16 output tile per block
__global__ __launch_bounds__(256) void refiner_kernel(
  const float* __restrict__ lr, const float* __restrict__ srg,
  const float* __restrict__ w0, const float* __restrict__ b0,
  const float* __restrict__ w1, const float* __restrict__ b1,
  const float* __restrict__ w2, const float* __restrict__ b2,
  float* __restrict__ out)
{
  __shared__ float x6s[6][22][22];
  __shared__ float r1as[48][20][20];
  __shared__ float r1bs[48][18][18];
  int tid = threadIdx.x;
  int gx0 = blockIdx.x*16, gy0 = blockIdx.y*16;

  // x6 = [lr_up(3), sr-lr_up(3)], zero outside image ('SAME' zero pad)
  for (int i = tid; i < 6*22*22; i += 256){
    int ch = i / 484; int rem = i - ch*484; int yy = rem / 22; int xx = rem - yy*22;
    int gy = gy0 - 3 + yy, gx = gx0 - 3 + xx;
    float v = 0.f;
    if (gy>=0 && gy<HWD && gx>=0 && gx<HWD){
      int c = (ch<3)?ch:(ch-3);
      float lu = lr_up_at(lr, c, gy, gx);
      v = (ch < 3) ? lu : (srg[c*NPIX + gy*HWD + gx] - lu);
    }
    x6s[ch][yy][xx] = v;
  }
  __syncthreads();

  // conv1: groups=3, in=2/group: x6 chans {2g,2g+1}
  for (int task = tid; task < 48*20; task += 256){
    int o = task / 20; int yy = task - o*20;
    int g = o >> 4;
    float acc[20];
    float bias = b0[o];
    #pragma unroll
    for (int j=0;j<20;++j) acc[j] = bias;
    #pragma unroll
    for (int ic=0; ic<2; ++ic){
      #pragma unroll
      for (int dyy=0; dyy<3; ++dyy){
        float row[22];
        #pragma unroll
        for (int j=0;j<22;++j) row[j] = x6s[g*2+ic][yy+dyy][j];
        #pragma unroll
        for (int dxx=0; dxx<3; ++dxx){
          float wv = w0[((o*2+ic)*3+dyy)*3+dxx];
          #pragma unroll
          for (int j=0;j<20;++j) acc[j] = fmaf(wv, row[j+dxx], acc[j]);
        }
      }
    }
    #pragma unroll
    for (int j=0;j<20;++j) r1as[o][yy][j] = gelu_f(acc[j]);
  }
  __syncthreads();

  // conv2: groups=3, in=16/group
  for (int task = tid; task < 48*18; task += 256){
    int o = task / 18; int yy = task - o*18;
    int g = o >> 4;
    float acc[18];
    float bias = b1[o];
    #pragma unroll
    for (int j=0;j<18;++j) acc[j] = bias;
    for (int ic=0; ic<16; ++ic){
      #pragma unroll
      for (int dyy=0; dyy<3; ++dyy){
        float row[20];
        #pragma unroll
        for (int j=0;j<20;++j) row[j] = r1as[g*16+ic][yy+dyy][j];
        #pragma unroll
        for (int dxx=0; dxx<3; ++dxx){
          float wv = w1[((o*16+ic)*3+dyy)*3+dxx];
          #pragma unroll
          for (int j=0;j<18;++j) acc[j] = fmaf(wv, row[j+dxx], acc[j]);
        }
      }
    }
    #pragma unroll
    for (int j=0;j<18;++j) r1bs[o][yy][j] = gelu_f(acc[j]);
  }
  __syncthreads();

  // conv3 (groups=3, 1 out/group) + sr2 + gray-residual fusion + clip
  {
    int ty = tid / 16, tx = tid - (tid/16)*16;
    int gy = gy0 + ty, gx = gx0 + tx;
    float res[3];
    #pragma unroll
    for (int c=0;c<3;++c){
      float a = b2[c];
      for (int ic=0;ic<16;++ic){
        #pragma unroll
        for (int dyy=0;dyy<3;++dyy){
          #pragma unroll
          for (int dxx=0;dxx<3;++dxx){
            a = fmaf(w2[((c*16+ic)*3+dyy)*3+dxx], r1bs[c*16+ic][ty+dyy][tx+dxx], a);
          }
        }
      }
      res[c] = a;
    }
    float lu[3], srv[3];
    #pragma unroll
    for (int c=0;c<3;++c){
      lu[c]  = lr_up_at(lr, c, gy, gx);
      srv[c] = srg[c*NPIX + gy*HWD + gx];
    }
    float delta = 0.2989f*(srv[0]+res[0]-lu[0])
                + 0.587f *(srv[1]+res[1]-lu[1])
                + 0.114f *(srv[2]+res[2]-lu[2]);
    #pragma unroll
    for (int c=0;c<3;++c){
      float o_ = lu[c] + delta;
      out[c*NPIX + gy*HWD + gx] = fminf(fmaxf(o_, 0.f), 1.f);
    }
  }
}

extern "C" void kernel_launch(void* const* d_in, const int* in_sizes, int n_in,
                              void* d_out, int out_size, void* d_ws, size_t ws_size,
                              hipStream_t stream){
  const float* lr  = (const float*)d_in[0];
  const float* ew0 = (const float*)d_in[1];  const float* eb0 = (const float*)d_in[2];
  const float* ew1 = (const float*)d_in[3];  const float* eb1 = (const float*)d_in[4];
  const float* ew2 = (const float*)d_in[5];  const float* eb2 = (const float*)d_in[6];
  const float* ew3 = (const float*)d_in[7];  const float* eb3 = (const float*)d_in[8];
  const float* cw0 = (const float*)d_in[9];  const float* cb0 = (const float*)d_in[10];
  const float* cw1 = (const float*)d_in[11]; const float* cb1 = (const float*)d_in[12];
  const float* mw0 = (const float*)d_in[13]; const float* mb0 = (const float*)d_in[14];
  const float* mw1 = (const float*)d_in[15]; const float* mb1 = (const float*)d_in[16];
  const float* mw2 = (const float*)d_in[17]; const float* mb2 = (const float*)d_in[18];
  const float* mw3 = (const float*)d_in[19]; const float* mb3 = (const float*)d_in[20];
  const float* mw4 = (const float*)d_in[21]; const float* mb4 = (const float*)d_in[22];
  const float* hkw = (const float*)d_in[23]; const float* hkb = (const float*)d_in[24];
  const float* hgw = (const float*)d_in[25]; const float* hgb = (const float*)d_in[26];
  const float* rw0 = (const float*)d_in[27]; const float* rb0 = (const float*)d_in[28];
  const float* rw1 = (const float*)d_in[29]; const float* rb1 = (const float*)d_in[30];
  const float* rw2 = (const float*)d_in[31]; const float* rb2 = (const float*)d_in[32];

  float* ws = (float*)d_ws;
  float* f0  = ws;                 // [64][96][96]
  float* f1  = ws + 589824;        // [64][96][96]
  float* srp = ws + 2*589824;      // [3][384][384]

  conv3x3_kernel<<<2304,256,0,stream>>>(lr, ew0, eb0, f0, 3);
  conv3x3_kernel<<<2304,256,0,stream>>>(f0, ew1, eb1, f1, 64);
  conv3x3_kernel<<<2304,256,0,stream>>>(f1, ew2, eb2, f0, 64);
  conv3x3_kernel<<<2304,256,0,stream>>>(f0, ew3, eb3, f1, 64);
  conv1x1_kernel<<<2304,256,0,stream>>>(f1, cw0, cb0, f0, 66, 1);  // +gelu
  conv1x1_kernel<<<2304,256,0,stream>>>(f0, cw1, cb1, f1, 64, 0);  // no gelu

  mlp_kernel<<<2304,512,0,stream>>>(f1, lr,
      mw0,mb0, mw1,mb1, mw2,mb2, mw3,mb3, mw4,mb4,
      hkw,hkb, hgw,hgb, srp);

  refiner_kernel<<<dim3(24,24),256,0,stream>>>(lr, srp,
      rw0,rb0, rw1,rb1, rw2,rb2, (float*)d_out);
}

// Round 2
// 591.102 us; speedup vs baseline: 5.6231x; 5.6231x over previous
//
#include <hip/hip_runtime.h>
#include <math.h>

#define LWI 96
#define LHI 96
#define HWD 384
#define NPIX 147456
#define LRPIX 9216
#define HID 256

typedef __attribute__((ext_vector_type(8))) _Float16 f16x8;
typedef __attribute__((ext_vector_type(16))) float f32x16;

__device__ __forceinline__ float gelu_f(float x){
  return 0.5f*x*(1.0f + erff(x*0.70710678118654752440f));
}

// fast gelu: x*sigmoid(2*0.79788456*(x+0.044715x^3)); |err| <= ~1e-3 abs
__device__ __forceinline__ float gelu_fast(float x){
  float x2 = x*x;
  float u = x*(-1.5957691216f - 0.0713548162f*x2);   // -2*inner
  float e = __expf(u);
  return x * __builtin_amdgcn_rcpf(1.0f + e);
}

// jax.image.resize 'bilinear' (half-pixel, clamp) at scale 4
__device__ __forceinline__ float lr_up_at(const float* __restrict__ lr, int c, int y, int x){
  float sy = (y+0.5f)*0.25f - 0.5f;
  float sx = (x+0.5f)*0.25f - 0.5f;
  float fy = floorf(sy), fx = floorf(sx);
  float ty = sy - fy, tx = sx - fx;
  int y0 = (int)fy, x0 = (int)fx;
  int y0c = min(max(y0,0),LHI-1), y1c = min(max(y0+1,0),LHI-1);
  int x0c = min(max(x0,0),LWI-1), x1c = min(max(x0+1,0),LWI-1);
  const float* p = lr + c*LRPIX;
  float v00 = p[y0c*LWI+x0c], v01 = p[y0c*LWI+x1c];
  float v10 = p[y1c*LWI+x0c], v11 = p[y1c*LWI+x1c];
  return (1.f-ty)*((1.f-tx)*v00 + tx*v01) + ty*((1.f-tx)*v10 + tx*v11);
}

__global__ __launch_bounds__(256) void conv3x3_kernel(
    const float* __restrict__ in, const float* __restrict__ w,
    const float* __restrict__ b, float* __restrict__ out, int Cin){
  int tid = blockIdx.x*256 + threadIdx.x;
  int o = tid / LRPIX; int rem = tid - o*LRPIX;
  int y = rem / LWI;   int x = rem - y*LWI;
  int ou = __builtin_amdgcn_readfirstlane(o);
  float acc = b[ou];
  const float* wo = w + ou*Cin*9;
  for (int i=0;i<Cin;++i){
    const float* inp = in + i*LRPIX;
    #pragma unroll
    for (int dy=0;dy<3;++dy){
      int yy = y + dy - 1;
      bool yok = (yy>=0 && yy<LHI);
      #pragma unroll
      for (int dx=0;dx<3;++dx){
        int xx = x + dx - 1;
        float v = (yok && xx>=0 && xx<LWI) ? inp[yy*LWI+xx] : 0.0f;
        acc = fmaf(wo[i*9 + dy*3 + dx], v, acc);
      }
    }
  }
  out[tid] = gelu_f(acc);
}

__global__ __launch_bounds__(256) void conv1x1_kernel(
    const float* __restrict__ in, const float* __restrict__ w,
    const float* __restrict__ b, float* __restrict__ out,
    int wstride, int dogelu){
  int tid = blockIdx.x*256 + threadIdx.x;
  int o = tid / LRPIX; int p = tid - o*LRPIX;
  int ou = __builtin_amdgcn_readfirstlane(o);
  float acc = b[ou];
  const float* wo = w + ou*wstride;
  for (int i=0;i<64;++i) acc = fmaf(wo[i], in[i*LRPIX+p], acc);
  out[tid] = dogelu ? gelu_f(acc) : acc;
}

// ---- pack weights (f32 [K][N] row-major) into f16 fragment-major order ----
// WB[layer]: [ks][cb(8)][slot(64)][e(8)], slot=(col&31)+32*((k&15)>>3), e=k&7
// layer sizes (f16): L0 (K=112): 28672; L1-4 (K=256): 65536; heads: 65536
__global__ __launch_bounds__(256) void pack_weights(
  const float* __restrict__ mw0, const float* __restrict__ mw1,
  const float* __restrict__ mw2, const float* __restrict__ mw3,
  const float* __restrict__ mw4, const float* __restrict__ hkw,
  const float* __restrict__ hgw,
  const float* __restrict__ mb0, const float* __restrict__ mb1,
  const float* __restrict__ mb2, const float* __restrict__ mb3,
  const float* __restrict__ mb4, const float* __restrict__ hkb,
  const float* __restrict__ hgb,
  _Float16* __restrict__ WB, float* __restrict__ biasAll)
{
  int i = blockIdx.x*256 + threadIdx.x;
  if (i < 356352){
    int layer, local;
    if (i < 28672){ layer = 0; local = i; }
    else { layer = 1 + ((i-28672)>>16); local = (i-28672)&65535; }
    int ks = local >> 12; int r = local & 4095;
    int cb = r >> 9; int s2 = r & 511; int slot = s2 >> 3; int e = s2 & 7;
    int col = cb*32 + (slot & 31); int g = slot >> 5;
    int k = ks*16 + g*8 + e;
    float v = 0.f;
    if (layer == 0){ if (k < 106) v = mw0[k*256+col]; }
    else if (layer == 1) v = mw1[k*256+col];
    else if (layer == 2) v = mw2[k*256+col];
    else if (layer == 3) v = mw3[k*256+col];
    else if (layer == 4) v = mw4[k*256+col];
    else { if (col < 196) v = hkw[k*196+col]; else if (col < 200) v = hgw[k*4+col-196]; }
    WB[i] = (_Float16)v;
  } else if (i < 356352+1536){
    int j = i - 356352; int layer = j>>8; int col = j&255;
    float v = 0.f;
    if (layer==0) v=mb0[col]; else if (layer==1) v=mb1[col]; else if(layer==2) v=mb2[col];
    else if(layer==3) v=mb3[col]; else if(layer==4) v=mb4[col];
    else { if (col<196) v=hkb[col]; else if(col<200) v=hgb[col-196]; }
    biasAll[j] = v;
  }
}

// ---- MFMA MLP: 64 px/block, 4 waves, wave w owns cols [64w,64w+64) ----
__global__ __launch_bounds__(256,2) void mlp_mfma_kernel(
  const float* __restrict__ feat, const float* __restrict__ lr,
  const _Float16* __restrict__ WB, const float* __restrict__ biasAll,
  float* __restrict__ sr)
{
  __shared__ _Float16 bufA[16384];   // 32KB: [bucket=ks*2+rb][slot(64)][e(8)]
  __shared__ _Float16 bufB[16384];
  const int t = threadIdx.x;
  const int lane = t & 63;
  const int w = t >> 6;          // wave 0..3
  const int rbw = lane >> 5;
  const int px = blockIdx.x*64 + lane;
  const int y = px / HWD; const int x = px - y*HWD;
  float lx = (x+0.5f)*0.25f - 0.5f;
  float ly = (y+0.5f)*0.25f - 0.5f;
  float cxf = fminf(fmaxf(rintf(lx),0.f),95.f);
  float cyf = fminf(fmaxf(rintf(ly),0.f),95.f);
  int cxi=(int)cxf, cyi=(int)cyf;
  float dxv=lx-cxf, dyv=ly-cyf;
  int base = cyi*LWI+cxi;

  // ---- z build (frag-packed f16) into bufA ----
  {
    auto zwrite = [&](int k, float v){
      int ks=k>>4, g=(k>>3)&1, e=k&7;
      bufA[(ks*2 + rbw)*512 + ((lane&31)+32*g)*8 + e] = (_Float16)v;
    };
    #pragma unroll
    for (int j=0;j<16;++j){ int c=w*16+j; zwrite(c, feat[c*LRPIX+base]); }
    if (w==0){
      float xn = (x+0.5f)/384.0f*2.0f - 1.0f;
      float s = sinf(xn*3.14159265358979323846f);
      float c = cosf(xn*3.14159265358979323846f);
      #pragma unroll
      for (int b=0;b<10;++b){
        zwrite(64+4*b+0, s); zwrite(64+4*b+1, c);
        float s2 = 2.f*s*c; float c2 = 1.f - 2.f*s*s;
        s=s2; c=c2;
      }
    } else if (w==1){
      float yn = (y+0.5f)/384.0f*2.0f - 1.0f;
      float s = sinf(yn*3.14159265358979323846f);
      float c = cosf(yn*3.14159265358979323846f);
      #pragma unroll
      for (int b=0;b<10;++b){
        zwrite(64+4*b+2, s); zwrite(64+4*b+3, c);
        float s2 = 2.f*s*c; float c2 = 1.f - 2.f*s*s;
        s=s2; c=c2;
      }
    } else if (w==2){
      zwrite(104, dxv); zwrite(105, dyv);
    } else {
      #pragma unroll
      for (int k=106;k<112;++k) zwrite(k, 0.f);
    }
  }
  __syncthreads();

  const int cb0 = 2*w, cb1 = 2*w+1;
  _Float16* cur = bufA; _Float16* nxt = bufB;
  const int WOFF[6] = {0,28672,94208,159744,225280,290816};

  // ---- 5 hidden layers ----
  for (int L=0; L<5; ++L){
    const _Float16* Wl = WB + WOFF[L];
    const int nks = (L==0)?7:16;
    f32x16 acc00{}, acc01{}, acc10{}, acc11{};
    for (int ks=0; ks<nks; ++ks){
      f16x8 a0 = *(const f16x8*)(cur + (ks*2+0)*512 + lane*8);
      f16x8 a1 = *(const f16x8*)(cur + (ks*2+1)*512 + lane*8);
      f16x8 b0 = *(const f16x8*)(Wl + (ks*8+cb0)*512 + lane*8);
      f16x8 b1 = *(const f16x8*)(Wl + (ks*8+cb1)*512 + lane*8);
      acc00 = __builtin_amdgcn_mfma_f32_32x32x16_f16(a0,b0,acc00,0,0,0);
      acc01 = __builtin_amdgcn_mfma_f32_32x32x16_f16(a0,b1,acc01,0,0,0);
      acc10 = __builtin_amdgcn_mfma_f32_32x32x16_f16(a1,b0,acc10,0,0,0);
      acc11 = __builtin_amdgcn_mfma_f32_32x32x16_f16(a1,b1,acc11,0,0,0);
    }
    const float* Bl = biasAll + L*256;
    auto epi = [&](const f32x16& acc, int rb, int cb){
      int colg = cb*32 + (lane&31);
      float bias = Bl[colg];
      int ks2 = colg>>4, g2=(colg>>3)&1, e2=colg&7;
      _Float16* dst = nxt + (ks2*2+rb)*512 + 32*g2*8 + e2;
      #pragma unroll
      for (int reg=0; reg<16; ++reg){
        int r5 = (reg&3) + 8*(reg>>2) + 4*(lane>>5);
        float v = acc[reg] + bias;
        dst[r5*8] = (_Float16)gelu_fast(v);
      }
    };
    epi(acc00,0,cb0); epi(acc01,0,cb1); epi(acc10,1,cb0); epi(acc11,1,cb1);
    __syncthreads();
    _Float16* tmp=cur; cur=nxt; nxt=tmp;
  }
  // cur == bufB (holds h5 frags)

  // ---- heads: K=256 -> 200 cols (196 klog + 4 glog), f32, col-major stride 65 ----
  float* klA = (float*)bufA;   // cols 0..120
  float* klB = (float*)bufB;   // cols 121..199
  {
    const _Float16* Wl = WB + WOFF[5];
    f32x16 acc00{}, acc01{}, acc10{}, acc11{};
    for (int ks=0; ks<16; ++ks){
      f16x8 a0 = *(const f16x8*)(cur + (ks*2+0)*512 + lane*8);
      f16x8 a1 = *(const f16x8*)(cur + (ks*2+1)*512 + lane*8);
      f16x8 b0 = *(const f16x8*)(Wl + (ks*8+cb0)*512 + lane*8);
      f16x8 b1 = *(const f16x8*)(Wl + (ks*8+cb1)*512 + lane*8);
      acc00 = __builtin_amdgcn_mfma_f32_32x32x16_f16(a0,b0,acc00,0,0,0);
      acc01 = __builtin_amdgcn_mfma_f32_32x32x16_f16(a0,b1,acc01,0,0,0);
      acc10 = __builtin_amdgcn_mfma_f32_32x32x16_f16(a1,b0,acc10,0,0,0);
      acc11 = __builtin_amdgcn_mfma_f32_32x32x16_f16(a1,b1,acc11,0,0,0);
    }
    __syncthreads();   // everyone done reading bufB before klog overwrites
    const float* Bl = biasAll + 5*256;
    auto epih = [&](const f32x16& acc, int rb, int cb){
      int colg = cb*32+(lane&31);
      if (colg >= 200) return;
      float bias = Bl[colg];
      float* dstc = (colg<121) ? (klA + colg*65) : (klB + (colg-121)*65);
      #pragma unroll
      for (int reg=0; reg<16; ++reg){
        int r5 = (reg&3)+8*(reg>>2)+4*(lane>>5);
        dstc[rb*32 + r5] = acc[reg] + bias;
      }
    };
    epih(acc00,0,cb0); epih(acc01,0,cb1); epih(acc10,1,cb0); epih(acc11,1,cb1);
  }
  __syncthreads();

  // ---- softmax per head + gate softmax; in-place -> gated kernel weights ----
  {
    int p = lane; int hd = w;
    auto KL = [&](int col)->float& {
      return (col<121) ? klA[col*65+p] : klB[(col-121)*65+p];
    };
    float g0=KL(196),g1=KL(197),g2=KL(198),g3=KL(199);
    float gm = fmaxf(fmaxf(g0,g1),fmaxf(g2,g3));
    float e0=__expf(g0-gm),e1=__expf(g1-gm),e2=__expf(g2-gm),e3=__expf(g3-gm);
    float gate = ((hd==0)?e0:(hd==1)?e1:(hd==2)?e2:e3)/(e0+e1+e2+e3);
    float m = -1e30f;
    for (int k=0;k<49;++k) m = fmaxf(m, KL(hd*49+k));
    float s = 0.f;
    for (int k=0;k<49;++k){ float e=__expf(KL(hd*49+k)-m); s+=e; KL(hd*49+k)=e; }
    float sc = gate/s;
    for (int k=0;k<49;++k) KL(hd*49+k) *= sc;
  }
  __syncthreads();

  // ---- apply mixed 7x7 kernel ----
  if (t < 192){
    int c = w;   // 0..2; lane==px-in-block so cxi/cyi valid
    const float* lrc = lr + c*LRPIX;
    auto klr = [&](int col)->float {
      return (col<121) ? klA[col*65+lane] : klB[(col-121)*65+lane];
    };
    float acc = 0.f;
    #pragma unroll
    for (int k=0;k<49;++k){
      float km = klr(k) + klr(49+k) + klr(98+k) + klr(147+k);
      int oy = k/7 - 3, ox = k - (k/7)*7 - 3;
      int nyy = min(max(cyi+oy,0),95), nxx = min(max(cxi+ox,0),95);
      acc = fmaf(km, lrc[nyy*LWI+nxx], acc);
    }
    sr[c*NPIX + px] = acc;
  }
}

// fused grouped-conv refiner + gray-residual fusion; 16x16 output tile per block
__global__ __launch_bounds__(256) void refiner_kernel(
  const float* __restrict__ lr, const float* __restrict__ srg,
  const float* __restrict__ w0, const float* __restrict__ b0,
  const float* __restrict__ w1, const float* __restrict__ b1,
  const float* __restrict__ w2, const float* __restrict__ b2,
  float* __restrict__ out)
{
  __shared__ float x6s[6][22][22];
  __shared__ float r1as[48][20][20];
  __shared__ float r1bs[48][18][18];
  int tid = threadIdx.x;
  int gx0 = blockIdx.x*16, gy0 = blockIdx.y*16;

  for (int i = tid; i < 6*22*22; i += 256){
    int ch = i / 484; int rem = i - ch*484; int yy = rem / 22; int xx = rem - yy*22;
    int gy = gy0 - 3 + yy, gx = gx0 - 3 + xx;
    float v = 0.f;
    if (gy>=0 && gy<HWD && gx>=0 && gx<HWD){
      int c = (ch<3)?ch:(ch-3);
      float lu = lr_up_at(lr, c, gy, gx);
      v = (ch < 3) ? lu : (srg[c*NPIX + gy*HWD + gx] - lu);
    }
    x6s[ch][yy][xx] = v;
  }
  __syncthreads();

  for (int task = tid; task < 48*20; task += 256){
    int o = task / 20; int yy = task - o*20;
    int g = o >> 4;
    float acc[20];
    float bias = b0[o];
    #pragma unroll
    for (int j=0;j<20;++j) acc[j] = bias;
    #pragma unroll
    for (int ic=0; ic<2; ++ic){
      #pragma unroll
      for (int dyy=0; dyy<3; ++dyy){
        float row[22];
        #pragma unroll
        for (int j=0;j<22;++j) row[j] = x6s[g*2+ic][yy+dyy][j];
        #pragma unroll
        for (int dxx=0; dxx<3; ++dxx){
          float wv = w0[((o*2+ic)*3+dyy)*3+dxx];
          #pragma unroll
          for (int j=0;j<20;++j) acc[j] = fmaf(wv, row[j+dxx], acc[j]);
        }
      }
    }
    #pragma unroll
    for (int j=0;j<20;++j) r1as[o][yy][j] = gelu_f(acc[j]);
  }
  __syncthreads();

  for (int task = tid; task < 48*18; task += 256){
    int o = task / 18; int yy = task - o*18;
    int g = o >> 4;
    float acc[18];
    float bias = b1[o];
    #pragma unroll
    for (int j=0;j<18;++j) acc[j] = bias;
    for (int ic=0; ic<16; ++ic){
      #pragma unroll
      for (int dyy=0; dyy<3; ++dyy){
        float row[20];
        #pragma unroll
        for (int j=0;j<20;++j) row[j] = r1as[g*16+ic][yy+dyy][j];
        #pragma unroll
        for (int dxx=0; dxx<3; ++dxx){
          float wv = w1[((o*16+ic)*3+dyy)*3+dxx];
          #pragma unroll
          for (int j=0;j<18;++j) acc[j] = fmaf(wv, row[j+dxx], acc[j]);
        }
      }
    }
    #pragma unroll
    for (int j=0;j<18;++j) r1bs[o][yy][j] = gelu_f(acc[j]);
  }
  __syncthreads();

  {
    int ty = tid / 16, tx = tid - (tid/16)*16;
    int gy = gy0 + ty, gx = gx0 + tx;
    float res[3];
    #pragma unroll
    for (int c=0;c<3;++c){
      float a = b2[c];
      for (int ic=0;ic<16;++ic){
        #pragma unroll
        for (int dyy=0;dyy<3;++dyy){
          #pragma unroll
          for (int dxx=0;dxx<3;++dxx){
            a = fmaf(w2[((c*16+ic)*3+dyy)*3+dxx], r1bs[c*16+ic][ty+dyy][tx+dxx], a);
          }
        }
      }
      res[c] = a;
    }
    float lu[3], srv[3];
    #pragma unroll
    for (int c=0;c<3;++c){
      lu[c]  = lr_up_at(lr, c, gy, gx);
      srv[c] = srg[c*NPIX + gy*HWD + gx];
    }
    float delta = 0.2989f*(srv[0]+res[0]-lu[0])
                + 0.587f *(srv[1]+res[1]-lu[1])
                + 0.114f *(srv[2]+res[2]-lu[2]);
    #pragma unroll
    for (int c=0;c<3;++c){
      float o_ = lu[c] + delta;
      out[c*NPIX + gy*HWD + gx] = fminf(fmaxf(o_, 0.f), 1.f);
    }
  }
}

extern "C" void kernel_launch(void* const* d_in, const int* in_sizes, int n_in,
                              void* d_out, int out_size, void* d_ws, size_t ws_size,
                              hipStream_t stream){
  const float* lr  = (const float*)d_in[0];
  const float* ew0 = (const float*)d_in[1];  const float* eb0 = (const float*)d_in[2];
  const float* ew1 = (const float*)d_in[3];  const float* eb1 = (const float*)d_in[4];
  const float* ew2 = (const float*)d_in[5];  const float* eb2 = (const float*)d_in[6];
  const float* ew3 = (const float*)d_in[7];  const float* eb3 = (const float*)d_in[8];
  const float* cw0 = (const float*)d_in[9];  const float* cb0 = (const float*)d_in[10];
  const float* cw1 = (const float*)d_in[11]; const float* cb1 = (const float*)d_in[12];
  const float* mw0 = (const float*)d_in[13]; const float* mb0 = (const float*)d_in[14];
  const float* mw1 = (const float*)d_in[15]; const float* mb1 = (const float*)d_in[16];
  const float* mw2 = (const float*)d_in[17]; const float* mb2 = (const float*)d_in[18];
  const float* mw3 = (const float*)d_in[19]; const float* mb3 = (const float*)d_in[20];
  const float* mw4 = (const float*)d_in[21]; const float* mb4 = (const float*)d_in[22];
  const float* hkw = (const float*)d_in[23]; const float* hkb = (const float*)d_in[24];
  const float* hgw = (const float*)d_in[25]; const float* hgb = (const float*)d_in[26];
  const float* rw0 = (const float*)d_in[27]; const float* rb0 = (const float*)d_in[28];
  const float* rw1 = (const float*)d_in[29]; const float* rb1 = (const float*)d_in[30];
  const float* rw2 = (const float*)d_in[31]; const float* rb2 = (const float*)d_in[32];

  float* ws = (float*)d_ws;
  float* f0  = ws;                     // [64][96][96]
  float* f1  = ws + 589824;            // [64][96][96]
  float* srp = ws + 2*589824;          // [3][384][384]
  _Float16* WB = (_Float16*)(ws + 1622016);   // 356352 f16
  float* biasAll = ws + 1622016 + 178176;     // 1536 f32

  pack_weights<<<1398,256,0,stream>>>(mw0,mw1,mw2,mw3,mw4,hkw,hgw,
      mb0,mb1,mb2,mb3,mb4,hkb,hgb, WB, biasAll);

  conv3x3_kernel<<<2304,256,0,stream>>>(lr, ew0, eb0, f0, 3);
  conv3x3_kernel<<<2304,256,0,stream>>>(f0, ew1, eb1, f1, 64);
  conv3x3_kernel<<<2304,256,0,stream>>>(f1, ew2, eb2, f0, 64);
  conv3x3_kernel<<<2304,256,0,stream>>>(f0, ew3, eb3, f1, 64);
  conv1x1_kernel<<<2304,256,0,stream>>>(f1, cw0, cb0, f0, 66, 1);
  conv1x1_kernel<<<2304,256,0,stream>>>(f0, cw1, cb1, f1, 64, 0);

  mlp_mfma_kernel<<<2304,256,0,stream>>>(f1, lr, WB, biasAll, srp);

  refiner_kernel<<<dim3(24,24),256,0,stream>>>(lr, srp,
      rw0,rb0, rw1,rb1, rw2,rb2, (float*)d_out);
}